// Round 3
// baseline (1592.447 us; speedup 1.0000x reference)
//
#include <hip/hip_runtime.h>
#include <cstddef>

#define N_NODES 16384
#define N_FEAT  16384
#define EMBED   64
#define BATCH   4096
#define N_EDGES 524288

typedef __attribute__((ext_vector_type(8))) short bf16x8;  // 8 bf16 = 4 VGPR (MFMA A/B frag)
typedef __attribute__((ext_vector_type(4))) float f32x4;   // MFMA C/D frag

// fp32 -> bf16 round-to-nearest-even (bit trick, sign-safe)
__device__ __forceinline__ ushort f32_to_bf16(float f) {
    unsigned u = __float_as_uint(f);
    return (ushort)((u + 0x7FFFu + ((u >> 16) & 1u)) >> 16);
}
__device__ __forceinline__ float bf16_to_f32(ushort h) {
    return __uint_as_float((unsigned)h << 16);
}

// split 8 fp32 (two float4) into hi/lo bf16x8 fragments
__device__ __forceinline__ void split8(float4 a, float4 b, bf16x8& h, bf16x8& l) {
    float f[8] = {a.x, a.y, a.z, a.w, b.x, b.y, b.z, b.w};
    #pragma unroll
    for (int j = 0; j < 8; ++j) {
        ushort hh = f32_to_bf16(f[j]);
        h[j] = (short)hh;
        l[j] = (short)f32_to_bf16(f[j] - bf16_to_f32(hh));
    }
}

// ---------------------------------------------------------------------------
// degree / dinv (deg buffer doubles as dinv after k_dinv)
__global__ void k_deg_init(float* __restrict__ deg) {
    int n = blockIdx.x * blockDim.x + threadIdx.x;
    if (n < N_NODES) deg[n] = 1.0f;            // self-loop
}
__global__ void k_deg_acc(const int* __restrict__ ei, float* __restrict__ deg) {
    int e = blockIdx.x * blockDim.x + threadIdx.x;
    if (e < N_EDGES) atomicAdd(&deg[ei[N_EDGES + e]], 1.0f);
}
__global__ void k_dinv(float* __restrict__ deg) {
    int n = blockIdx.x * blockDim.x + threadIdx.x;
    if (n < N_NODES) deg[n] = rsqrtf(deg[n]);
}

// ---------------------------------------------------------------------------
// CSR build: exclusive prefix scan of in-edge counts (deg-1), 1 block.
__global__ __launch_bounds__(1024) void k_scan(const float* __restrict__ deg,
                                               int* __restrict__ off,
                                               int* __restrict__ cur) {
    __shared__ int part[1024];
    const int t = threadIdx.x;
    int c[16];
    int s = 0;
    #pragma unroll
    for (int i = 0; i < 16; ++i) {
        c[i] = (int)deg[t * 16 + i] - 1;       // in-edges only (self-loop excluded)
        s += c[i];
    }
    part[t] = s;
    __syncthreads();
    for (int d = 1; d < 1024; d <<= 1) {       // Hillis-Steele inclusive scan
        int v = (t >= d) ? part[t - d] : 0;
        __syncthreads();
        part[t] += v;
        __syncthreads();
    }
    int run = (t == 0) ? 0 : part[t - 1];      // exclusive
    #pragma unroll
    for (int i = 0; i < 16; ++i) {
        off[t * 16 + i] = run;
        cur[t * 16 + i] = run;
        run += c[i];
    }
    if (t == 1023) off[N_NODES] = run;         // == N_EDGES
}

// bucket edges by dst: srcs[off[d] .. off[d+1]) = list of sources into d
__global__ void k_scatter(const int* __restrict__ ei, int* __restrict__ cur,
                          int* __restrict__ srcs) {
    int e = blockIdx.x * blockDim.x + threadIdx.x;
    if (e < N_EDGES) {
        int s = ei[e];
        int d = ei[N_EDGES + e];
        srcs[atomicAdd(&cur[d], 1)] = s;
    }
}

// ---------------------------------------------------------------------------
// Pack W (fp32 [16384][64]) into MFMA B-fragment order, split into hi/lo bf16.
// Frag f = (split*2048 + kstep*4 + coltile); lane l holds 8 bf16 at
// k = kstep*32 + (l>>4)*8 + j, n = coltile*16 + (l&15). 4 MB total, L2-hot.
__global__ void k_wpack(const float* __restrict__ W, short* __restrict__ Wpk) {
    int tid = blockIdx.x * blockDim.x + threadIdx.x;   // 262144
    int lane = tid & 63;
    int f = tid >> 6;                                  // 0..4095
    int ct = f & 3;
    int ks = (f >> 2) & 511;
    int sp = f >> 11;                                  // 0 = hi, 1 = lo
    int n = ct * 16 + (lane & 15);
    int kbase = ks * 32 + (lane >> 4) * 8;
    bf16x8 r;
    #pragma unroll
    for (int j = 0; j < 8; ++j) {
        float w = W[(size_t)(kbase + j) * EMBED + n];
        ushort h = f32_to_bf16(w);
        r[j] = (sp == 0) ? (short)h : (short)f32_to_bf16(w - bf16_to_f32(h));
    }
    *(bf16x8*)(Wpk + (size_t)f * 512 + lane * 8) = r;
}

// ---------------------------------------------------------------------------
// xw_part[kpl] = X[:, kslice] @ W[kslice, :] via bf16 split-2 MFMA
// (terms hh + hl + lh; ~2^-17 rel trunc).
//
// BARRIER-FREE / LDS-FREE design: each wave owns a 16-row x 64-col output
// tile, so its A data (16 rows x 2048 K-slice) is wave-private -> no LDS
// staging, no __syncthreads in the K-loop at all. A streams global->VGPR
// with a static 2-deep ring (a0/a1, unroll-2: all indices compile-time,
// rule #20). B frags load per step from packed Wpk (L2-resident: all blocks
// on XCD j share K-slice j since kpl = blockIdx&7 = XCD round-robin).
// Compiler inserts counted vmcnt waits (G7). ~95 VGPR, no spill at the
// 128 cap, 4-5 waves/SIMD -> latency hidden by TLP + 2-step prefetch.
#define KSPLIT 8
#define KCHUNK (N_FEAT / KSPLIT)   // 2048
#define NSTEP (KCHUNK / 32)        // 64

__global__ __launch_bounds__(256, 4) void k_gemm(const float* __restrict__ X,
                                                 const short* __restrict__ Wpk,
                                                 float* __restrict__ xw_part) {
    const int t = threadIdx.x;
    const int kpl = blockIdx.x & 7;                // K-slice == XCD (blockIdx % 8)
    const int rb  = blockIdx.x >> 3;               // row block 0..255 (64 rows each)
    const int w = t >> 6;
    const int lane = t & 63;
    const int g = lane >> 4;                       // k-group 0..3
    const int lr = lane & 15;                      // frag row 0..15

    // A-frag source: lane serves row (rb*64 + w*16 + lr), k = step*32 + g*8 + j
    const float* ap = X + (size_t)(rb * 64 + w * 16 + lr) * N_FEAT
                        + (size_t)kpl * KCHUNK + g * 8;
    const short* bp0 = Wpk + (size_t)(kpl * NSTEP * 4) * 512 + lane * 8;

    f32x4 acc[4] = {};

    // prologue: prefetch steps 0 and 1
    float4 a0_0 = *(const float4*)(ap);
    float4 a0_1 = *(const float4*)(ap + 4);
    float4 a1_0 = *(const float4*)(ap + 32);
    float4 a1_1 = *(const float4*)(ap + 36);

    for (int kt = 0; kt < NSTEP; kt += 2) {
        // ---- step kt (payload a0) ----
        {
            const short* bp = bp0 + (size_t)kt * 2048;
            bf16x8 bh[4], bl[4];
            #pragma unroll
            for (int ct = 0; ct < 4; ++ct) {
                bh[ct] = *(const bf16x8*)(bp + ct * 512);
                bl[ct] = *(const bf16x8*)(bp + ct * 512 + 1048576);
            }
            bf16x8 ah, al;
            split8(a0_0, a0_1, ah, al);
            if (kt + 2 < NSTEP) {                  // prefetch step kt+2 into a0
                a0_0 = *(const float4*)(ap + (size_t)(kt + 2) * 32);
                a0_1 = *(const float4*)(ap + (size_t)(kt + 2) * 32 + 4);
            }
            #pragma unroll
            for (int ct = 0; ct < 4; ++ct) {
                acc[ct] = __builtin_amdgcn_mfma_f32_16x16x32_bf16(ah, bh[ct], acc[ct], 0, 0, 0);
                acc[ct] = __builtin_amdgcn_mfma_f32_16x16x32_bf16(ah, bl[ct], acc[ct], 0, 0, 0);
                acc[ct] = __builtin_amdgcn_mfma_f32_16x16x32_bf16(al, bh[ct], acc[ct], 0, 0, 0);
            }
        }
        // ---- step kt+1 (payload a1) ----
        {
            const short* bp = bp0 + (size_t)(kt + 1) * 2048;
            bf16x8 bh[4], bl[4];
            #pragma unroll
            for (int ct = 0; ct < 4; ++ct) {
                bh[ct] = *(const bf16x8*)(bp + ct * 512);
                bl[ct] = *(const bf16x8*)(bp + ct * 512 + 1048576);
            }
            bf16x8 ah, al;
            split8(a1_0, a1_1, ah, al);
            if (kt + 3 < NSTEP) {                  // prefetch step kt+3 into a1
                a1_0 = *(const float4*)(ap + (size_t)(kt + 3) * 32);
                a1_1 = *(const float4*)(ap + (size_t)(kt + 3) * 32 + 4);
            }
            #pragma unroll
            for (int ct = 0; ct < 4; ++ct) {
                acc[ct] = __builtin_amdgcn_mfma_f32_16x16x32_bf16(ah, bh[ct], acc[ct], 0, 0, 0);
                acc[ct] = __builtin_amdgcn_mfma_f32_16x16x32_bf16(ah, bl[ct], acc[ct], 0, 0, 0);
                acc[ct] = __builtin_amdgcn_mfma_f32_16x16x32_bf16(al, bh[ct], acc[ct], 0, 0, 0);
            }
        }
    }

    // epilogue: C/D layout col = lane&15, row = (lane>>4)*4 + reg (m89-verified)
    float* part = xw_part + (size_t)kpl * (N_NODES * EMBED);
    #pragma unroll
    for (int ct = 0; ct < 4; ++ct)
        #pragma unroll
        for (int r = 0; r < 4; ++r) {
            int row = rb * 64 + w * 16 + g * 4 + r;
            part[(size_t)row * EMBED + ct * 16 + lr] = acc[ct][r];
        }
}

// xw = sum over KSPLIT partial slices (36 MB traffic, ~10 us)
__global__ void k_reduce(const float4* __restrict__ part, float4* __restrict__ xw) {
    int i = blockIdx.x * blockDim.x + threadIdx.x;   // 262144 float4s
    float4 s = part[i];
    #pragma unroll
    for (int p = 1; p < KSPLIT; ++p) {
        float4 v = part[(size_t)p * (N_NODES * EMBED / 4) + i];
        s.x += v.x; s.y += v.y; s.z += v.z; s.w += v.w;
    }
    xw[i] = s;
}

// ---------------------------------------------------------------------------
// agg[n] = dinv[n] * ( dinv[n]*xw[n] + sum_{s in CSR[n]} dinv[s]*xw[s] )
// One wave per dst node; register accumulation, no atomics.
__global__ void k_gather(const int* __restrict__ off, const int* __restrict__ srcs,
                         const float* __restrict__ xw, const float* __restrict__ dinv,
                         float* __restrict__ agg) {
    int n = blockIdx.x * 4 + (threadIdx.x >> 6);
    int lane = threadIdx.x & 63;
    float dn = dinv[n];
    float acc = xw[(size_t)n * EMBED + lane] * dn;   // self-loop (x dn at end -> dn^2)
    int i = off[n], i1 = off[n + 1];
    for (; i + 1 < i1; i += 2) {                     // 2-way unroll: parallel loads
        int s0 = srcs[i], s1 = srcs[i + 1];
        float a0 = xw[(size_t)s0 * EMBED + lane] * dinv[s0];
        float a1 = xw[(size_t)s1 * EMBED + lane] * dinv[s1];
        acc += a0 + a1;
    }
    if (i < i1) {
        int s = srcs[i];
        acc += xw[(size_t)s * EMBED + lane] * dinv[s];
    }
    agg[(size_t)n * EMBED + lane] = acc * dn;
}

// ---------------------------------------------------------------------------
// out[b] = w_lin[i0] + w_lin[i1] + b_lin + dot(emb[i0]+b_gcn, emb[i1]+b_gcn)
__global__ void k_final(const int* __restrict__ x, const float* __restrict__ agg,
                        const float* __restrict__ b_gcn, const float* __restrict__ w_lin,
                        const float* __restrict__ b_lin, float* __restrict__ out) {
    int b = blockIdx.x * (blockDim.x >> 6) + (threadIdx.x >> 6);
    int lane = threadIdx.x & 63;
    if (b >= BATCH) return;
    int i0 = x[2 * b + 0];
    int i1 = x[2 * b + 1];
    float bg = b_gcn[lane];
    float e0 = agg[(size_t)i0 * EMBED + lane] + bg;
    float e1 = agg[(size_t)i1 * EMBED + lane] + bg;
    float p = e0 * e1;
    #pragma unroll
    for (int off = 32; off > 0; off >>= 1) p += __shfl_down(p, off, 64);
    if (lane == 0) out[b] = p + w_lin[i0] + w_lin[i1] + b_lin[0];
}

// ---------------------------------------------------------------------------
extern "C" void kernel_launch(void* const* d_in, const int* in_sizes, int n_in,
                              void* d_out, int out_size, void* d_ws, size_t ws_size,
                              hipStream_t stream) {
    (void)in_sizes; (void)n_in; (void)out_size; (void)ws_size;

    const int*   x   = (const int*)d_in[0];    // [BATCH, 2]
    const float* X   = (const float*)d_in[1];  // [N_NODES, N_FEAT]
    const int*   ei  = (const int*)d_in[2];    // [2, N_EDGES]
    const float* W   = (const float*)d_in[3];  // [N_FEAT, EMBED]
    const float* bg  = (const float*)d_in[4];  // [EMBED]
    const float* wl  = (const float*)d_in[5];  // [N_NODES]
    const float* bl  = (const float*)d_in[6];  // [1]
    float* out = (float*)d_out;                // [BATCH]

    // workspace layout:
    //   0      : xw     4 MB
    //   4 MB   : Wpk    4 MB   (aliased by agg: Wpk dead before k_gather writes)
    //   8 MB   : dinv   64 KB
    //   +128 KB: off    64 KB+4
    //   +256 KB: cur    64 KB
    //   +512 KB: srcs   2 MB
    //   16 MB  : xw_part 32 MB (KSPLIT slices)
    char* ws = (char*)d_ws;
    float* xw      = (float*)(ws);
    short* Wpk     = (short*)(ws + (size_t)(4 << 20));
    float* agg     = (float*)(ws + (size_t)(4 << 20));
    float* dinv    = (float*)(ws + (size_t)(8 << 20));
    int*   off     = (int*)  (ws + (size_t)(8 << 20) + (1 << 17));
    int*   cur     = (int*)  (ws + (size_t)(8 << 20) + (1 << 18));
    int*   srcs    = (int*)  (ws + (size_t)(8 << 20) + (1 << 19));
    float* xw_part = (float*)(ws + (size_t)(16 << 20));

    k_deg_init<<<N_NODES / 256, 256, 0, stream>>>(dinv);
    k_deg_acc<<<N_EDGES / 256, 256, 0, stream>>>(ei, dinv);
    k_scan<<<1, 1024, 0, stream>>>(dinv, off, cur);       // needs raw deg
    k_dinv<<<N_NODES / 256, 256, 0, stream>>>(dinv);      // deg -> rsqrt(deg)
    k_scatter<<<N_EDGES / 256, 256, 0, stream>>>(ei, cur, srcs);

    k_wpack<<<1024, 256, 0, stream>>>(W, Wpk);
    k_gemm<<<(N_NODES / 64) * KSPLIT, 256, 0, stream>>>(X, Wpk, xw_part);
    k_reduce<<<(N_NODES * EMBED / 4) / 256, 256, 0, stream>>>((const float4*)xw_part, (float4*)xw);

    k_gather<<<N_NODES / 4, 256, 0, stream>>>(off, srcs, xw, dinv, agg);
    k_final<<<BATCH / 4, 256, 0, stream>>>(x, agg, bg, wl, bl, out);
}